// Round 5
// baseline (227.171 us; speedup 1.0000x reference)
//
#include <hip/hip_runtime.h>

#define T_TOK  16384
#define IN_F   1024
#define OUT_F  1024
#define NE     8
#define BM     128
#define BN     128
#define BK     32
#define NITER  (IN_F / BK)    // 32
#define NTHREADS 256
#define ROW_TILE_SLOTS 136    // max sum of ceil(len_e/128) = 128 + 8

typedef __bf16 bf16;
typedef bf16  bf16x4 __attribute__((ext_vector_type(4)));
typedef bf16  bf16x8 __attribute__((ext_vector_type(8)));
typedef float f32x4  __attribute__((ext_vector_type(4)));

#define NW_ELEM ((size_t)NE * OUT_F * IN_F)     // 8,388,608
#define WS_NEED (NW_ELEM * sizeof(bf16))        // ~16.8 MB

// ---------------- Phase 1: W fp32 -> bf16 (x stays fp32, converted in-loop) --
__global__ __launch_bounds__(NTHREADS)
void cvt_w_bf16(const float* __restrict__ w, bf16* __restrict__ wb)
{
    size_t i = ((size_t)blockIdx.x * NTHREADS + threadIdx.x) * 8;
    f32x4 v0 = *(const f32x4*)(w + i);
    f32x4 v1 = *(const f32x4*)(w + i + 4);
    bf16x8 h;
    #pragma unroll
    for (int j = 0; j < 4; ++j) { h[j] = (bf16)v0[j]; h[4 + j] = (bf16)v1[j]; }
    *(bf16x8*)(wb + i) = h;
}

// ---------------- Phase 2: software-pipelined grouped GEMM ------------------
// One barrier per k-iter, LDS double-buffer. After the barrier we ISSUE the
// next tile's loads (A: fp32->regs; B: global_load_lds DMA into the other
// buffer), then run MFMA on the current buffer, then cvt+ds_write next A.
// The implicit vmcnt(0) drain at the barrier thus lands AFTER compute.
__global__ __launch_bounds__(NTHREADS)
void grouped_gemm_pipe(const float* __restrict__ x,
                       const bf16* __restrict__ wb,
                       const int*  __restrict__ seg_lens,
                       float* __restrict__ out)
{
    __shared__ __align__(16) bf16 As[2][BM * BK];
    __shared__ __align__(16) bf16 Bs[2][BN * BK];

    const int m    = blockIdx.y;          // row-tile slot
    const int col0 = blockIdx.x * BN;     // output-feature tile

    int e_sel = -1, row0 = 0, rows = 0;
    {
        int start = 0, acct = 0;
        #pragma unroll
        for (int e = 0; e < NE; ++e) {
            int len = seg_lens[e];
            int nt  = (len + BM - 1) >> 7;
            if (e_sel < 0 && m >= acct && m < acct + nt) {
                e_sel = e;
                row0  = start + (m - acct) * BM;
                int rem = start + len - row0;
                rows = rem < BM ? rem : BM;
            }
            acct  += nt;
            start += len;
        }
    }
    if (e_sel < 0) return;   // surplus slot (block-uniform, before any barrier)

    const int tid  = threadIdx.x;
    const int lane = tid & 63;
    const int wave = tid >> 6;
    const int wm   = (wave >> 1) * 64;
    const int wn   = (wave & 1) * 64;
    const int quad = lane >> 4;
    const int l16  = lane & 15;

    // A staging map: 2 threads/row, 16 contiguous k each (64 B fp32 per thread)
    const int rowA = tid >> 1;
    const int koff = (tid & 1) * 16;
    int rgA = row0 + rowA;
    if (rgA > T_TOK - 1) rgA = T_TOK - 1;     // clamp partial last tile
    const float* aptr = x + (size_t)rgA * IN_F + koff;
    const int aoff = rowA * BK + koff;

    const bf16* wbase = wb + ((size_t)e_sel * OUT_F + col0) * IN_F;

    // ---- prologue: stage k=0 into buffer 0 ----
    {
        f32x4 a0 = *(const f32x4*)(aptr + 0);
        f32x4 a1 = *(const f32x4*)(aptr + 4);
        f32x4 a2 = *(const f32x4*)(aptr + 8);
        f32x4 a3 = *(const f32x4*)(aptr + 12);
        #pragma unroll
        for (int t = 0; t < 2; ++t) {
            int c = t * NTHREADS + tid;
            const bf16* gp = wbase + (size_t)(c >> 2) * IN_F + (c & 3) * 8;
            __builtin_amdgcn_global_load_lds(
                (const __attribute__((address_space(1))) void*)gp,
                (__attribute__((address_space(3))) void*)(&Bs[0][c * 8]),
                16, 0, 0);
        }
        bf16x8 h0, h1;
        #pragma unroll
        for (int j = 0; j < 4; ++j) {
            h0[j] = (bf16)a0[j]; h0[4 + j] = (bf16)a1[j];
            h1[j] = (bf16)a2[j]; h1[4 + j] = (bf16)a3[j];
        }
        *(bf16x8*)(&As[0][aoff])     = h0;
        *(bf16x8*)(&As[0][aoff + 8]) = h1;
    }

    f32x4 acc[4][4] = {};

    for (int i = 0; i < NITER; ++i) {
        __syncthreads();   // buf[i&1] ready; prev iter's DMA drained here (post-compute)
        const int cur = i & 1, nxt = cur ^ 1;
        const int kn  = ((i + 1) & (NITER - 1)) * BK;   // wraps on last iter (wasted, harmless)

        // ---- issue next-tile loads (A regs first so ds_write can wait vmcnt(2)) ----
        f32x4 a0 = *(const f32x4*)(aptr + kn);
        f32x4 a1 = *(const f32x4*)(aptr + kn + 4);
        f32x4 a2 = *(const f32x4*)(aptr + kn + 8);
        f32x4 a3 = *(const f32x4*)(aptr + kn + 12);
        #pragma unroll
        for (int t = 0; t < 2; ++t) {
            int c = t * NTHREADS + tid;
            const bf16* gp = wbase + (size_t)(c >> 2) * IN_F + kn + (c & 3) * 8;
            __builtin_amdgcn_global_load_lds(
                (const __attribute__((address_space(1))) void*)gp,
                (__attribute__((address_space(3))) void*)(&Bs[nxt][c * 8]),
                16, 0, 0);
        }

        // ---- compute current tile ----
        bf16x8 af[4], bfr[4];
        #pragma unroll
        for (int t = 0; t < 4; ++t)
            af[t] = *(const bf16x8*)(&As[cur][(wm + t * 16 + l16) * BK + quad * 8]);
        #pragma unroll
        for (int u = 0; u < 4; ++u)
            bfr[u] = *(const bf16x8*)(&Bs[cur][(wn + u * 16 + l16) * BK + quad * 8]);

        #pragma unroll
        for (int t = 0; t < 4; ++t)
            #pragma unroll
            for (int u = 0; u < 4; ++u)
                acc[t][u] = __builtin_amdgcn_mfma_f32_16x16x32_bf16(
                    af[t], bfr[u], acc[t][u], 0, 0, 0);

        // ---- stage next A tile into the other buffer (after MFMA) ----
        bf16x8 h0, h1;
        #pragma unroll
        for (int j = 0; j < 4; ++j) {
            h0[j] = (bf16)a0[j]; h0[4 + j] = (bf16)a1[j];
            h1[j] = (bf16)a2[j]; h1[4 + j] = (bf16)a3[j];
        }
        *(bf16x8*)(&As[nxt][aoff])     = h0;
        *(bf16x8*)(&As[nxt][aoff + 8]) = h1;
    }

    // ---- epilogue: C/D layout col=lane&15, row=quad*4+reg (m89/m91) ----
    #pragma unroll
    for (int t = 0; t < 4; ++t) {
        #pragma unroll
        for (int r = 0; r < 4; ++r) {
            int row = wm + t * 16 + quad * 4 + r;
            if (row < rows) {
                size_t ob = (size_t)(row0 + row) * OUT_F + col0;
                #pragma unroll
                for (int u = 0; u < 4; ++u)
                    out[ob + wn + u * 16 + l16] = acc[t][u][r];
            }
        }
    }
}

// ---------------- Fallback: fused fp32 kernel (if ws too small) -------------
__global__ __launch_bounds__(NTHREADS)
void grouped_gemm_f32io_fused(const float* __restrict__ x,
                              const float* __restrict__ wgt,
                              const int*  __restrict__ seg_lens,
                              float* __restrict__ out)
{
    __shared__ __align__(16) bf16 As[BM * BK];
    __shared__ __align__(16) bf16 Bs[BN * BK];

    const int m    = blockIdx.y;
    const int col0 = blockIdx.x * BN;

    int e_sel = -1, row0 = 0, rows = 0;
    {
        int start = 0, acct = 0;
        #pragma unroll
        for (int e = 0; e < NE; ++e) {
            int len = seg_lens[e];
            int nt  = (len + BM - 1) >> 7;
            if (e_sel < 0 && m >= acct && m < acct + nt) {
                e_sel = e;
                row0  = start + (m - acct) * BM;
                int rem = start + len - row0;
                rows = rem < BM ? rem : BM;
            }
            acct  += nt;
            start += len;
        }
    }
    if (e_sel < 0) return;

    const int tid  = threadIdx.x;
    const int lane = tid & 63;
    const int wave = tid >> 6;
    const int wm   = (wave >> 1) * 64;
    const int wn   = (wave & 1) * 64;
    const int quad = lane >> 4;
    const int l16  = lane & 15;

    const float* wbase = wgt + ((size_t)e_sel * OUT_F + (size_t)col0) * IN_F;

    f32x4 acc[4][4] = {};

    for (int k0 = 0; k0 < IN_F; k0 += BK) {
        f32x4 a_st[4], b_st[4];
        #pragma unroll
        for (int t = 0; t < 4; ++t) {
            int c  = t * NTHREADS + tid;
            int rg = row0 + (c >> 3);
            if (rg > T_TOK - 1) rg = T_TOK - 1;
            a_st[t] = *(const f32x4*)(x + (size_t)rg * IN_F + k0 + (c & 7) * 4);
            b_st[t] = *(const f32x4*)(wbase + (size_t)(c >> 3) * IN_F + k0 + (c & 7) * 4);
        }
        __syncthreads();
        #pragma unroll
        for (int t = 0; t < 4; ++t) {
            int c = t * NTHREADS + tid;
            bf16x4 ha, hb;
            #pragma unroll
            for (int j = 0; j < 4; ++j) { ha[j] = (bf16)a_st[t][j]; hb[j] = (bf16)b_st[t][j]; }
            *(bf16x4*)(&As[(c >> 3) * BK + (c & 7) * 4]) = ha;
            *(bf16x4*)(&Bs[(c >> 3) * BK + (c & 7) * 4]) = hb;
        }
        __syncthreads();

        bf16x8 af[4], bfr[4];
        #pragma unroll
        for (int t = 0; t < 4; ++t)
            af[t] = *(const bf16x8*)(&As[(wm + t * 16 + l16) * BK + quad * 8]);
        #pragma unroll
        for (int u = 0; u < 4; ++u)
            bfr[u] = *(const bf16x8*)(&Bs[(wn + u * 16 + l16) * BK + quad * 8]);

        #pragma unroll
        for (int t = 0; t < 4; ++t)
            #pragma unroll
            for (int u = 0; u < 4; ++u)
                acc[t][u] = __builtin_amdgcn_mfma_f32_16x16x32_bf16(
                    af[t], bfr[u], acc[t][u], 0, 0, 0);
    }

    #pragma unroll
    for (int t = 0; t < 4; ++t) {
        #pragma unroll
        for (int r = 0; r < 4; ++r) {
            int row = wm + t * 16 + quad * 4 + r;
            if (row < rows) {
                size_t ob = (size_t)(row0 + row) * OUT_F + col0;
                #pragma unroll
                for (int u = 0; u < 4; ++u)
                    out[ob + wn + u * 16 + l16] = acc[t][u][r];
            }
        }
    }
}

extern "C" void kernel_launch(void* const* d_in, const int* in_sizes, int n_in,
                              void* d_out, int out_size, void* d_ws, size_t ws_size,
                              hipStream_t stream) {
    const float* x   = (const float*)d_in[0];
    const float* wgt = (const float*)d_in[1];
    const int*   seg = (const int*)d_in[2];
    float* out = (float*)d_out;

    dim3 block(NTHREADS, 1, 1);
    dim3 grid2(OUT_F / BN, ROW_TILE_SLOTS, 1);

    if (ws_size >= WS_NEED) {
        bf16* wb = (bf16*)d_ws;
        // Phase 1: W fp32 -> bf16 (~50 MB traffic, memory-bound)
        cvt_w_bf16<<<(int)(NW_ELEM / 8 / NTHREADS), block, 0, stream>>>(wgt, wb);
        // Phase 2: pipelined grouped GEMM (x converted in-loop)
        grouped_gemm_pipe<<<grid2, block, 0, stream>>>(x, wb, seg, out);
    } else {
        grouped_gemm_f32io_fused<<<grid2, block, 0, stream>>>(x, wgt, seg, out);
    }
}